// Round 15
// baseline (171.489 us; speedup 1.0000x reference)
//
#include <hip/hip_runtime.h>
#include <hip/hip_bf16.h>

#define B_ 8
#define C_ 128
#define N_ 4096   // H*W = 64*64

typedef float  f32x4  __attribute__((ext_vector_type(4)));

__device__ __forceinline__ float fp8tof(unsigned u, int sel) {
    switch (sel & 3) {
        case 0:  return __builtin_amdgcn_cvt_f32_fp8(u, 0);
        case 1:  return __builtin_amdgcn_cvt_f32_fp8(u, 1);
        case 2:  return __builtin_amdgcn_cvt_f32_fp8(u, 2);
        default: return __builtin_amdgcn_cvt_f32_fp8(u, 3);
    }
}

// ---------------------------------------------------------------------------
// K1: channel softmax over C for each (b, n). EXACT R14 version.
// ---------------------------------------------------------------------------
__global__ __launch_bounds__(128) void chan_softmax(const float* __restrict__ x,
                                                    float* __restrict__ xs,
                                                    unsigned char* __restrict__ vT8,
                                                    float* __restrict__ S)
{
    int idx = blockIdx.x * 128 + threadIdx.x;     // (b, n) flattened, 32768 total
    if (idx < B_ * C_) S[idx] = 0.0f;

    int b = idx >> 12;
    int n = idx & (N_ - 1);

    const float* xp = x + (size_t)b * C_ * N_ + n;

    float xv[C_];
    #pragma unroll
    for (int c = 0; c < C_; ++c) xv[c] = xp[(size_t)c * N_];   // independent loads

    float m = xv[0];
    #pragma unroll
    for (int c = 1; c < C_; ++c) m = fmaxf(m, xv[c]);

    float s = 0.f;
    #pragma unroll
    for (int c = 0; c < C_; ++c) { xv[c] = __expf(xv[c] - m); s += xv[c]; }
    float inv = 1.f / s;

    float* op = xs + (size_t)b * C_ * N_ + n;
    uint4* vp = reinterpret_cast<uint4*>(vT8 + ((size_t)b * N_ + n) * C_);

    #pragma unroll
    for (int c0 = 0; c0 < C_; c0 += 16) {
        unsigned pk[4];
        #pragma unroll
        for (int wi = 0; wi < 4; ++wi) {
            float v0 = xv[c0 + wi * 4 + 0] * inv;
            float v1 = xv[c0 + wi * 4 + 1] * inv;
            float v2 = xv[c0 + wi * 4 + 2] * inv;
            float v3 = xv[c0 + wi * 4 + 3] * inv;
            op[(size_t)(c0 + wi * 4 + 0) * N_] = v0;
            op[(size_t)(c0 + wi * 4 + 1) * N_] = v1;
            op[(size_t)(c0 + wi * 4 + 2) * N_] = v2;
            op[(size_t)(c0 + wi * 4 + 3) * N_] = v3;
            unsigned u = __builtin_amdgcn_cvt_pk_fp8_f32(v0, v1, 0, false);
            u = __builtin_amdgcn_cvt_pk_fp8_f32(v2, v3, u, true);
            pk[wi] = u;
        }
        uint4 q; q.x = pk[0]; q.y = pk[1]; q.z = pk[2]; q.w = pk[3];
        vp[c0 >> 4] = q;   // 16 B store, row-contiguous
    }
}

// ---------------------------------------------------------------------------
// K2: S[b][c] += partial column sums of vT (fp8 decode). EXACT R13/R14 version.
// ---------------------------------------------------------------------------
__global__ __launch_bounds__(256) void colsum(const unsigned char* __restrict__ vT8,
                                              float* __restrict__ S)
{
    int bid   = blockIdx.x;
    int b     = bid & 7;
    int chunk = bid >> 3;                 // 0..31 (128 rows each)
    int t     = threadIdx.x;
    int g     = t & 31;
    int sub   = t >> 5;                   // 0..7 (16 rows each)

    const unsigned* base = reinterpret_cast<const unsigned*>(vT8 + (size_t)b * N_ * C_)
                         + (size_t)(chunk * 128 + sub * 16) * (C_ / 4) + g;

    float a0 = 0.f, a1 = 0.f, a2 = 0.f, a3 = 0.f;
    #pragma unroll 4
    for (int r = 0; r < 16; ++r) {
        unsigned u = base[(size_t)r * (C_ / 4)];  // 4 fp8
        a0 += __builtin_amdgcn_cvt_f32_fp8(u, 0);
        a1 += __builtin_amdgcn_cvt_f32_fp8(u, 1);
        a2 += __builtin_amdgcn_cvt_f32_fp8(u, 2);
        a3 += __builtin_amdgcn_cvt_f32_fp8(u, 3);
    }

    __shared__ float st[8][C_];
    st[sub][g * 4 + 0] = a0;
    st[sub][g * 4 + 1] = a1;
    st[sub][g * 4 + 2] = a2;
    st[sub][g * 4 + 3] = a3;
    __syncthreads();
    if (t < C_) {
        float s = 0.f;
        #pragma unroll
        for (int k = 0; k < 8; ++k) s += st[k][t];
        atomicAdd(&S[b * C_ + t], s);
    }
}

// ---------------------------------------------------------------------------
// K3: attention[b][i][j] = exp(<v_i,v_j>) * inv_i, single pass.
// R14 structure; ONE change: LDS staging in two 32-row halves ([4][32][68] =
// 34.8 KB/block instead of 69.6) + __launch_bounds__(256,3) -> 3 blocks/CU
// (12 waves/CU vs 8). Mechanism: more resident waves cover store-queue
// backpressure parking (fillBuffer-style TLP). Same store pattern & math.
// ---------------------------------------------------------------------------
__global__ __launch_bounds__(256, 3) void att_write(const unsigned char* __restrict__ vT8,
                                                    const float* __restrict__ S,
                                                    float* __restrict__ att)
{
    __shared__ float lds[4][32][68];      // per-wave [32][68] padded HALF-tiles

    int bid = blockIdx.x;
    int b = bid & 7;                       // batch pinned to XCD
    int rowblock = bid >> 3;
    int rowbase = rowblock * 64;
    int rot = rowblock & 15;               // jt phase rotation (kept from R14)

    int w    = threadIdx.x >> 6;           // wave id: column window within tile
    int lane = threadIdx.x & 63;
    int r16  = lane & 15;
    int kg   = lane >> 4;

    const unsigned char* base = vT8 + (size_t)b * N_ * C_;

    // A fragments: rows rowbase..rowbase+63, full K=128. 16 x long = 32 VGPR.
    long a8[4][4];
    #pragma unroll
    for (int mi = 0; mi < 4; ++mi)
        #pragma unroll
        for (int ks = 0; ks < 4; ++ks)
            a8[mi][ks] = *reinterpret_cast<const long*>(
                base + (size_t)(rowbase + mi * 16 + r16) * C_ + ks * 32 + kg * 8);

    // inv_i = 1/(N + v_i.S): first-order denominator (validated R4+).
    const float* Sb = S + b * C_;
    float inv_src[4];
    #pragma unroll
    for (int mi = 0; mi < 4; ++mi) {
        float d = 0.f;
        #pragma unroll
        for (int ks = 0; ks < 4; ++ks) {
            int k0 = ks * 32 + kg * 8;
            unsigned lo = (unsigned)(a8[mi][ks] & 0xffffffffu);
            unsigned hi = (unsigned)(((unsigned long)a8[mi][ks]) >> 32);
            #pragma unroll
            for (int j = 0; j < 4; ++j) d += fp8tof(lo, j) * Sb[k0 + j];
            #pragma unroll
            for (int j = 0; j < 4; ++j) d += fp8tof(hi, j) * Sb[k0 + 4 + j];
        }
        d += __shfl_xor(d, 16, 64);
        d += __shfl_xor(d, 32, 64);
        inv_src[mi] = 1.0f / ((float)N_ + d);
    }

    float* ab = att + (size_t)b * N_ * N_;
    float* myl = &lds[w][0][0];

    // prologue: B-frags for first (rotated) tile
    long bb8[4][4];
    #pragma unroll
    for (int ks = 0; ks < 4; ++ks)
        #pragma unroll
        for (int nj = 0; nj < 4; ++nj)
            bb8[ks][nj] = *reinterpret_cast<const long*>(
                base + (size_t)(rot * 256 + w * 64 + nj * 16 + r16) * C_ + ks * 32 + kg * 8);

    #pragma unroll 1
    for (int jt0 = 0; jt0 < 16; ++jt0) {
        int jt = (jt0 + rot) & 15;
        int colbase = jt * 256 + w * 64;

        f32x4 acc[4][4] = {};
        #pragma unroll
        for (int ks = 0; ks < 4; ++ks)
            #pragma unroll
            for (int mi = 0; mi < 4; ++mi)
                #pragma unroll
                for (int nj = 0; nj < 4; ++nj)
                    acc[mi][nj] = __builtin_amdgcn_mfma_f32_16x16x32_fp8_fp8(
                        a8[mi][ks], bb8[ks][nj], acc[mi][nj], 0, 0, 0);

        // prefetch next tile's B-frags (WAR reuse) BEFORE the stores.
        if (jt0 < 15) {
            int pf = (((jt0 + 1 + rot) & 15) * 256) + w * 64;
            #pragma unroll
            for (int ks = 0; ks < 4; ++ks)
                #pragma unroll
                for (int nj = 0; nj < 4; ++nj)
                    bb8[ks][nj] = *reinterpret_cast<const long*>(
                        base + (size_t)(pf + nj * 16 + r16) * C_ + ks * 32 + kg * 8);
        }

        // two half-tile passes through the 32-row staging buffer
        #pragma unroll
        for (int h = 0; h < 2; ++h) {
            // stage rows h*32..h*32+31 (mi = 2h, 2h+1)
            #pragma unroll
            for (int mh = 0; mh < 2; ++mh) {
                int mi = h * 2 + mh;
                #pragma unroll
                for (int nj = 0; nj < 4; ++nj)
                    #pragma unroll
                    for (int r = 0; r < 4; ++r)
                        myl[(mh * 16 + kg * 4 + r) * 68 + nj * 16 + r16] = acc[mi][nj][r];
            }

            asm volatile("s_waitcnt lgkmcnt(0)" ::: "memory");
            __builtin_amdgcn_sched_barrier(0);

            // readback: lane covers row p*4+kg (local 0..31), cols 4*r16..+3
            // NONTEMPORAL dwordx4, 4 rows x 256 B contiguous per instruction.
            #pragma unroll
            for (int p = 0; p < 8; ++p) {
                int lrow = p * 4 + kg;                   // 0..31 within half
                int grow = h * 32 + lrow;                // 0..63 within tile
                f32x4 o = *reinterpret_cast<f32x4*>(myl + lrow * 68 + 4 * r16);
                float iv = __shfl(inv_src[(h * 8 + p) >> 2], (((h * 8 + p) * 4) & 15) + kg, 64);
                #pragma unroll
                for (int i = 0; i < 4; ++i) o[i] = __expf(o[i]) * iv;
                __builtin_nontemporal_store(o,
                    reinterpret_cast<f32x4*>(&ab[(size_t)(rowbase + grow) * N_ + colbase + 4 * r16]));
            }
            // ds_writes of next half wait on these reads via lgkm ordering.
            asm volatile("s_waitcnt lgkmcnt(0)" ::: "memory");
            __builtin_amdgcn_sched_barrier(0);
        }
    }
}

// ---------------------------------------------------------------------------
// K4: out = gamma * (V @ attention^T) + xs. EXACT R13/R14 version.
// ---------------------------------------------------------------------------
__global__ __launch_bounds__(256) void pv_update(const float* __restrict__ gamma,
                                                 const unsigned char* __restrict__ vT8,
                                                 const float* __restrict__ att,
                                                 float* __restrict__ out)
{
    float g = gamma[0];
    if (g == 0.0f) return;

    int b  = blockIdx.y;
    int n0 = blockIdx.x * 128 + (threadIdx.x >> 7) * 64;
    int c  = threadIdx.x & 127;

    const unsigned char* vb = vT8 + (size_t)b * N_ * C_;

    for (int i = 0; i < 64; ++i) {
        int n = n0 + i;
        const float* arow = att + ((size_t)b * N_ + n) * N_;
        float acc = 0.f;
        for (int m = 0; m < N_; ++m)
            acc += __builtin_amdgcn_cvt_f32_fp8((unsigned)vb[(size_t)m * C_ + c], 0) * arow[m];
        size_t oi = ((size_t)b * C_ + c) * N_ + n;
        out[oi] = g * acc + out[oi];
    }
}

// ---------------------------------------------------------------------------
extern "C" void kernel_launch(void* const* d_in, const int* in_sizes, int n_in,
                              void* d_out, int out_size, void* d_ws, size_t ws_size,
                              hipStream_t stream)
{
    const float* x     = (const float*)d_in[0];
    const float* gamma = (const float*)d_in[1];

    float* out = (float*)d_out;                        // [B][C][N]  (4,194,304 f32)
    float* att = out + (size_t)B_ * C_ * N_;           // [B][N][N]  (134,217,728 f32)
    unsigned char* vT8 = (unsigned char*)d_ws;         // [B][N][C]  fp8, 4 MB
    float* S   = (float*)(vT8 + (size_t)B_ * N_ * C_); // [B][C] f32, 4 KB

    chan_softmax<<<256, 128, 0, stream>>>(x, out, vT8, S);
    colsum<<<256, 256, 0, stream>>>(vT8, S);
    att_write<<<(N_ / 64) * B_, 256, 0, stream>>>(vT8, S, att);
    pv_update<<<dim3(32, B_), 256, 0, stream>>>(gamma, vT8, att, out);
}

// Round 16
// 134.790 us; speedup vs baseline: 1.2723x; 1.2723x over previous
//
#include <hip/hip_runtime.h>
#include <hip/hip_bf16.h>

#define B_ 8
#define C_ 128
#define N_ 4096   // H*W = 64*64

typedef float  f32x4  __attribute__((ext_vector_type(4)));

__device__ __forceinline__ float fp8tof(unsigned u, int sel) {
    switch (sel & 3) {
        case 0:  return __builtin_amdgcn_cvt_f32_fp8(u, 0);
        case 1:  return __builtin_amdgcn_cvt_f32_fp8(u, 1);
        case 2:  return __builtin_amdgcn_cvt_f32_fp8(u, 2);
        default: return __builtin_amdgcn_cvt_f32_fp8(u, 3);
    }
}

// ---------------------------------------------------------------------------
// K1: channel softmax over C for each (b, n). EXACT R14 version.
// ---------------------------------------------------------------------------
__global__ __launch_bounds__(128) void chan_softmax(const float* __restrict__ x,
                                                    float* __restrict__ xs,
                                                    unsigned char* __restrict__ vT8,
                                                    float* __restrict__ S)
{
    int idx = blockIdx.x * 128 + threadIdx.x;     // (b, n) flattened, 32768 total
    if (idx < B_ * C_) S[idx] = 0.0f;

    int b = idx >> 12;
    int n = idx & (N_ - 1);

    const float* xp = x + (size_t)b * C_ * N_ + n;

    float xv[C_];
    #pragma unroll
    for (int c = 0; c < C_; ++c) xv[c] = xp[(size_t)c * N_];   // independent loads

    float m = xv[0];
    #pragma unroll
    for (int c = 1; c < C_; ++c) m = fmaxf(m, xv[c]);

    float s = 0.f;
    #pragma unroll
    for (int c = 0; c < C_; ++c) { xv[c] = __expf(xv[c] - m); s += xv[c]; }
    float inv = 1.f / s;

    float* op = xs + (size_t)b * C_ * N_ + n;
    uint4* vp = reinterpret_cast<uint4*>(vT8 + ((size_t)b * N_ + n) * C_);

    #pragma unroll
    for (int c0 = 0; c0 < C_; c0 += 16) {
        unsigned pk[4];
        #pragma unroll
        for (int wi = 0; wi < 4; ++wi) {
            float v0 = xv[c0 + wi * 4 + 0] * inv;
            float v1 = xv[c0 + wi * 4 + 1] * inv;
            float v2 = xv[c0 + wi * 4 + 2] * inv;
            float v3 = xv[c0 + wi * 4 + 3] * inv;
            op[(size_t)(c0 + wi * 4 + 0) * N_] = v0;
            op[(size_t)(c0 + wi * 4 + 1) * N_] = v1;
            op[(size_t)(c0 + wi * 4 + 2) * N_] = v2;
            op[(size_t)(c0 + wi * 4 + 3) * N_] = v3;
            unsigned u = __builtin_amdgcn_cvt_pk_fp8_f32(v0, v1, 0, false);
            u = __builtin_amdgcn_cvt_pk_fp8_f32(v2, v3, u, true);
            pk[wi] = u;
        }
        uint4 q; q.x = pk[0]; q.y = pk[1]; q.z = pk[2]; q.w = pk[3];
        vp[c0 >> 4] = q;   // 16 B store, row-contiguous
    }
}

// ---------------------------------------------------------------------------
// K2: S[b][c] += partial column sums of vT (fp8 decode). EXACT R13/R14 version.
// ---------------------------------------------------------------------------
__global__ __launch_bounds__(256) void colsum(const unsigned char* __restrict__ vT8,
                                              float* __restrict__ S)
{
    int bid   = blockIdx.x;
    int b     = bid & 7;
    int chunk = bid >> 3;                 // 0..31 (128 rows each)
    int t     = threadIdx.x;
    int g     = t & 31;
    int sub   = t >> 5;                   // 0..7 (16 rows each)

    const unsigned* base = reinterpret_cast<const unsigned*>(vT8 + (size_t)b * N_ * C_)
                         + (size_t)(chunk * 128 + sub * 16) * (C_ / 4) + g;

    float a0 = 0.f, a1 = 0.f, a2 = 0.f, a3 = 0.f;
    #pragma unroll 4
    for (int r = 0; r < 16; ++r) {
        unsigned u = base[(size_t)r * (C_ / 4)];  // 4 fp8
        a0 += __builtin_amdgcn_cvt_f32_fp8(u, 0);
        a1 += __builtin_amdgcn_cvt_f32_fp8(u, 1);
        a2 += __builtin_amdgcn_cvt_f32_fp8(u, 2);
        a3 += __builtin_amdgcn_cvt_f32_fp8(u, 3);
    }

    __shared__ float st[8][C_];
    st[sub][g * 4 + 0] = a0;
    st[sub][g * 4 + 1] = a1;
    st[sub][g * 4 + 2] = a2;
    st[sub][g * 4 + 3] = a3;
    __syncthreads();
    if (t < C_) {
        float s = 0.f;
        #pragma unroll
        for (int k = 0; k < 8; ++k) s += st[k][t];
        atomicAdd(&S[b * C_ + t], s);
    }
}

// ---------------------------------------------------------------------------
// K3: attention[b][i][j] = exp(<v_i,v_j>) * inv_i, single pass.
// R14 math/MFMA/prefetch; ONE structural change: BLOCK-SHARED staging tile
// [64][260] + __syncthreads(), so the store phase emits FULL-ROW stores:
// each instruction = 64 lanes x 16 B = 1 KB fully contiguous in one attention
// row (16 instrs/jt/wave as before, but 16 KB-strided 256 B runs -> 1 KB
// runs; 4x fewer DRAM page visits for the 537 MB stream). iv is row-uniform
// per instruction, preloaded once per wave from inv_lds (no per-jt shuffles).
// ---------------------------------------------------------------------------
__global__ __launch_bounds__(256, 2) void att_write(const unsigned char* __restrict__ vT8,
                                                    const float* __restrict__ S,
                                                    float* __restrict__ att)
{
    __shared__ float tile[64][260];       // block-shared 64 x 256 staging (+pad)
    __shared__ float inv_lds[64];

    int bid = blockIdx.x;
    int b = bid & 7;                       // batch pinned to XCD
    int rowblock = bid >> 3;
    int rowbase = rowblock * 64;
    int rot = rowblock & 15;               // jt phase rotation (kept from R14)

    int w    = threadIdx.x >> 6;           // wave id: column window within tile
    int lane = threadIdx.x & 63;
    int r16  = lane & 15;
    int kg   = lane >> 4;

    const unsigned char* base = vT8 + (size_t)b * N_ * C_;

    // A fragments: rows rowbase..rowbase+63, full K=128. 16 x long = 32 VGPR.
    long a8[4][4];
    #pragma unroll
    for (int mi = 0; mi < 4; ++mi)
        #pragma unroll
        for (int ks = 0; ks < 4; ++ks)
            a8[mi][ks] = *reinterpret_cast<const long*>(
                base + (size_t)(rowbase + mi * 16 + r16) * C_ + ks * 32 + kg * 8);

    // inv_i = 1/(N + v_i.S): first-order denominator (validated R4+).
    // All 4 waves compute identical values (A-frags don't depend on w);
    // wave 0 publishes to inv_lds.
    const float* Sb = S + b * C_;
    #pragma unroll
    for (int mi = 0; mi < 4; ++mi) {
        float d = 0.f;
        #pragma unroll
        for (int ks = 0; ks < 4; ++ks) {
            int k0 = ks * 32 + kg * 8;
            unsigned lo = (unsigned)(a8[mi][ks] & 0xffffffffu);
            unsigned hi = (unsigned)(((unsigned long)a8[mi][ks]) >> 32);
            #pragma unroll
            for (int j = 0; j < 4; ++j) d += fp8tof(lo, j) * Sb[k0 + j];
            #pragma unroll
            for (int j = 0; j < 4; ++j) d += fp8tof(hi, j) * Sb[k0 + 4 + j];
        }
        d += __shfl_xor(d, 16, 64);
        d += __shfl_xor(d, 32, 64);
        if (threadIdx.x < 16) inv_lds[mi * 16 + r16] = 1.0f / ((float)N_ + d);
    }
    __syncthreads();

    // per-wave iv for its 16 store rows (w*16 .. w*16+15), row-uniform values
    float iv_reg[16];
    #pragma unroll
    for (int p = 0; p < 16; ++p) iv_reg[p] = inv_lds[w * 16 + p];

    float* ab = att + (size_t)b * N_ * N_;

    // prologue: B-frags for first (rotated) tile
    long bb8[4][4];
    #pragma unroll
    for (int ks = 0; ks < 4; ++ks)
        #pragma unroll
        for (int nj = 0; nj < 4; ++nj)
            bb8[ks][nj] = *reinterpret_cast<const long*>(
                base + (size_t)(rot * 256 + w * 64 + nj * 16 + r16) * C_ + ks * 32 + kg * 8);

    #pragma unroll 1
    for (int jt0 = 0; jt0 < 16; ++jt0) {
        int jt = (jt0 + rot) & 15;

        f32x4 acc[4][4] = {};
        #pragma unroll
        for (int ks = 0; ks < 4; ++ks)
            #pragma unroll
            for (int mi = 0; mi < 4; ++mi)
                #pragma unroll
                for (int nj = 0; nj < 4; ++nj)
                    acc[mi][nj] = __builtin_amdgcn_mfma_f32_16x16x32_fp8_fp8(
                        a8[mi][ks], bb8[ks][nj], acc[mi][nj], 0, 0, 0);

        // prefetch next tile's B-frags (WAR reuse) BEFORE the stores.
        if (jt0 < 15) {
            int pf = (((jt0 + 1 + rot) & 15) * 256) + w * 64;
            #pragma unroll
            for (int ks = 0; ks < 4; ++ks)
                #pragma unroll
                for (int nj = 0; nj < 4; ++nj)
                    bb8[ks][nj] = *reinterpret_cast<const long*>(
                        base + (size_t)(pf + nj * 16 + r16) * C_ + ks * 32 + kg * 8);
        }

        // stage this wave's quadrant into the BLOCK tile:
        // row = mi*16+kg*4+r, col = w*64 + nj*16 + r16
        #pragma unroll
        for (int mi = 0; mi < 4; ++mi)
            #pragma unroll
            for (int nj = 0; nj < 4; ++nj)
                #pragma unroll
                for (int r = 0; r < 4; ++r)
                    tile[mi * 16 + kg * 4 + r][w * 64 + nj * 16 + r16] = acc[mi][nj][r];

        __syncthreads();

        // store phase: wave w owns rows w*16..w*16+15; one instruction per row
        // = 64 lanes x 16 B = 1 KB fully contiguous.
        #pragma unroll
        for (int p = 0; p < 16; ++p) {
            int row = w * 16 + p;
            f32x4 o = *reinterpret_cast<const f32x4*>(&tile[row][lane * 4]);
            float iv = iv_reg[p];
            #pragma unroll
            for (int i = 0; i < 4; ++i) o[i] = __expf(o[i]) * iv;
            __builtin_nontemporal_store(o,
                reinterpret_cast<f32x4*>(&ab[(size_t)(rowbase + row) * N_ + jt * 256 + lane * 4]));
        }

        __syncthreads();   // tile reusable next jt
    }
}

// ---------------------------------------------------------------------------
// K4: out = gamma * (V @ attention^T) + xs. EXACT R13/R14 version.
// ---------------------------------------------------------------------------
__global__ __launch_bounds__(256) void pv_update(const float* __restrict__ gamma,
                                                 const unsigned char* __restrict__ vT8,
                                                 const float* __restrict__ att,
                                                 float* __restrict__ out)
{
    float g = gamma[0];
    if (g == 0.0f) return;

    int b  = blockIdx.y;
    int n0 = blockIdx.x * 128 + (threadIdx.x >> 7) * 64;
    int c  = threadIdx.x & 127;

    const unsigned char* vb = vT8 + (size_t)b * N_ * C_;

    for (int i = 0; i < 64; ++i) {
        int n = n0 + i;
        const float* arow = att + ((size_t)b * N_ + n) * N_;
        float acc = 0.f;
        for (int m = 0; m < N_; ++m)
            acc += __builtin_amdgcn_cvt_f32_fp8((unsigned)vb[(size_t)m * C_ + c], 0) * arow[m];
        size_t oi = ((size_t)b * C_ + c) * N_ + n;
        out[oi] = g * acc + out[oi];
    }
}

// ---------------------------------------------------------------------------
extern "C" void kernel_launch(void* const* d_in, const int* in_sizes, int n_in,
                              void* d_out, int out_size, void* d_ws, size_t ws_size,
                              hipStream_t stream)
{
    const float* x     = (const float*)d_in[0];
    const float* gamma = (const float*)d_in[1];

    float* out = (float*)d_out;                        // [B][C][N]  (4,194,304 f32)
    float* att = out + (size_t)B_ * C_ * N_;           // [B][N][N]  (134,217,728 f32)
    unsigned char* vT8 = (unsigned char*)d_ws;         // [B][N][C]  fp8, 4 MB
    float* S   = (float*)(vT8 + (size_t)B_ * N_ * C_); // [B][C] f32, 4 KB

    chan_softmax<<<256, 128, 0, stream>>>(x, out, vT8, S);
    colsum<<<256, 256, 0, stream>>>(vT8, S);
    att_write<<<(N_ / 64) * B_, 256, 0, stream>>>(vT8, S, att);
    pv_update<<<dim3(32, B_), 256, 0, stream>>>(gamma, vT8, att, out);
}